// Round 13
// baseline (571.940 us; speedup 1.0000x reference)
//
#include <hip/hip_runtime.h>

#define IDIM 512
#define MIXD 32
#define HID 96
#define BB 256
#define TT 512
#define TROWS 32

typedef float f32x2 __attribute__((ext_vector_type(2)));
typedef float f32x4 __attribute__((ext_vector_type(4)));

#define EXP2(x) __builtin_amdgcn_exp2f(x)

template <int CTRL>
__device__ __forceinline__ float dpp_shl_add(float x) {
    int m = __builtin_amdgcn_update_dpp(0, __float_as_int(x), CTRL, 0xf, 0xf, true);
    return x + __int_as_float(m);
}
__device__ __forceinline__ float octet_reduce_lane0(float x) {
    x = dpp_shl_add<0x104>(x);   // row_shl:4
    x = dpp_shl_add<0x102>(x);   // row_shl:2
    x = dpp_shl_add<0x101>(x);   // row_shl:1
    return x;
}

// ---------------- K1: z = x @ W_mix^T (unchanged from R12 — proven) ---------
__global__ __launch_bounds__(256) void k_mix(const float* __restrict__ x,
                                             const float* __restrict__ Wmix,
                                             float* __restrict__ z) {
    __shared__ __align__(16) float sx[TROWS * IDIM];   // 64 KB
    const int tid = threadIdx.x;
    const int mg = tid >> 3, ks = tid & 7;

    f32x2 w[32];
    #pragma unroll
    for (int i = 0; i < 16; ++i) {
        const int cj = (i + 2 * ks) & 15;
        f32x4 v = *(const f32x4*)(Wmix + (size_t)mg * IDIM + ks * 64 + cj * 4);
        w[2*i] = v.xy; w[2*i+1] = v.zw;
    }

    const size_t rowbase = (size_t)blockIdx.x * 256;
    const float* xb = x + rowbase * IDIM;

    f32x4 st[16];
    #pragma unroll
    for (int i = 0; i < 16; ++i)
        st[i] = *(const f32x4*)(xb + (size_t)(tid + 256 * i) * 4);

    for (int t = 0; t < 8; ++t) {
        #pragma unroll
        for (int i = 0; i < 16; ++i)
            *(f32x4*)(&sx[(tid + 256 * i) * 4]) = st[i];
        __syncthreads();

        if (t + 1 < 8) {
            const float* xn = xb + (size_t)(t + 1) * TROWS * IDIM;
            #pragma unroll
            for (int i = 0; i < 16; ++i)
                st[i] = *(const f32x4*)(xn + (size_t)(tid + 256 * i) * 4);
        }

        float* zp = z + (rowbase + (size_t)t * TROWS) * MIXD + mg;
        for (int r = 0; r < TROWS; ++r) {
            const float* rp = sx + r * IDIM + ks * 64;
            f32x2 acc = {0.f, 0.f};
            #pragma unroll
            for (int i = 0; i < 16; ++i) {
                f32x4 v = *(const f32x4*)(rp + ((i + 2 * ks) & 15) * 4);
                acc = __builtin_elementwise_fma(w[2*i],   v.xy, acc);
                acc = __builtin_elementwise_fma(w[2*i+1], v.zw, acc);
            }
            float s = octet_reduce_lane0(acc.x + acc.y);
            if (ks == 0) zp[(size_t)r * MIXD] = s;
        }
        __syncthreads();
    }
}

// ---------------- K2: GRU scan + head, TWO batch elements per block ---------
// 256 threads = 4 waves, grid = 128 (b-pair per block). Octet (o = tid&7)
// serves j0, j0+32, j0+64 for BOTH b0 and b1: weights are SHARED (same j),
// while the two b-chains are independent -> their LDS-latency / fma / exp
// dependency chains interleave WITHIN the wave, hiding the serial path that
// pinned R8-R12 at ~1300 cy/step (1 block/CU = no other work to overlap).
__global__ __launch_bounds__(256, 1) void k_scan(const float* __restrict__ z,
                                                 const float* __restrict__ Wih,
                                                 const float* __restrict__ Whh,
                                                 const float* __restrict__ bih,
                                                 const float* __restrict__ bhh,
                                                 const float* __restrict__ Whead,
                                                 const float* __restrict__ bhead,
                                                 const float* __restrict__ Wmix,
                                                 float* __restrict__ y) {
    const int b0  = blockIdx.x * 2;
    const int tid = threadIdx.x;
    const int j0  = tid >> 3;     // 0..31
    const int o   = tid & 7;      // 0..7
    const float L  = 1.4426950408889634f;   // log2(e)
    const float L2 = 2.8853900817779268f;   // 2*log2(e)

    __shared__ __align__(16) float sz[2][256 * MIXD];  // 64 KB (per-b chunk)
    __shared__ __align__(16) float shp[2][2][HID];     // [b][pp][j]
    __shared__ __align__(16) float szn[2][MIXD];

    // ---- weights (SHARED across the two b's) ----
    f32x2 whr[3][6], whu[3][6], whn[3][6], wir[3][2], wiu[3][2], win[3][2];
    float br[3], bu[3], bxn[3], bhn[3];
    #pragma unroll
    for (int i = 0; i < 3; ++i) {
        const int j = j0 + 32 * i;
        #pragma unroll
        for (int c = 0; c < 3; ++c) {
            f32x4 v = *(const f32x4*)(Whh + (size_t)(j        ) * HID + o * 12 + c * 4);
            v *= L;  whr[i][2*c] = v.xy; whr[i][2*c+1] = v.zw;
        }
        #pragma unroll
        for (int c = 0; c < 3; ++c) {
            f32x4 v = *(const f32x4*)(Whh + (size_t)(j +   HID) * HID + o * 12 + c * 4);
            v *= L;  whu[i][2*c] = v.xy; whu[i][2*c+1] = v.zw;
        }
        #pragma unroll
        for (int c = 0; c < 3; ++c) {
            f32x4 v = *(const f32x4*)(Whh + (size_t)(j + 2*HID) * HID + o * 12 + c * 4);
            v *= L2; whn[i][2*c] = v.xy; whn[i][2*c+1] = v.zw;
        }
        {
            f32x4 v = *(const f32x4*)(Wih + (size_t)(j        ) * MIXD + o * 4);
            v *= L;  wir[i][0] = v.xy; wir[i][1] = v.zw;
        }
        {
            f32x4 v = *(const f32x4*)(Wih + (size_t)(j +   HID) * MIXD + o * 4);
            v *= L;  wiu[i][0] = v.xy; wiu[i][1] = v.zw;
        }
        {
            f32x4 v = *(const f32x4*)(Wih + (size_t)(j + 2*HID) * MIXD + o * 4);
            v *= L2; win[i][0] = v.xy; win[i][1] = v.zw;
        }
        br[i]  = (o == 0) ? L  * (bih[j]       + bhh[j])       : 0.f;
        bu[i]  = (o == 0) ? L  * (bih[j + HID] + bhh[j + HID]) : 0.f;
        bxn[i] = (o == 0) ? L2 * bih[j + 2*HID] : 0.f;
        bhn[i] = (o == 0) ? L2 * bhh[j + 2*HID] : 0.f;
    }

    float hown[3][2] = {{0.f,0.f},{0.f,0.f},{0.f,0.f}};
    if (tid < HID) { shp[0][0][tid] = 0.f; shp[1][0][tid] = 0.f; }

    const f32x4* zb0 = (const f32x4*)(z + (size_t)(b0    ) * TT * MIXD);
    const f32x4* zb1 = (const f32x4*)(z + (size_t)(b0 + 1) * TT * MIXD);
    f32x4* sz40 = (f32x4*)sz[0];
    f32x4* sz41 = (f32x4*)sz[1];

    for (int c = 0; c < TT / 256; ++c) {
        #pragma unroll
        for (int i = 0; i < 8; ++i) {
            sz40[tid + 256 * i] = zb0[c * 2048 + tid + 256 * i];
            sz41[tid + 256 * i] = zb1[c * 2048 + tid + 256 * i];
        }
        __syncthreads();

        for (int tt = 0; tt < 256; ++tt) {
            const int t = (c << 8) + tt;
            const int pr = t & 1, pw = (t + 1) & 1;

            // both b's data: two independent dep chains from here on
            const f32x4 z4a = *(const f32x4*)(sz[0] + tt * MIXD + o * 4);
            const f32x4 z4b = *(const f32x4*)(sz[1] + tt * MIXD + o * 4);
            const float* hra = shp[0][pr];
            const float* hrb = shp[1][pr];
            const f32x4 ha0 = *(const f32x4*)(hra + o * 12);
            const f32x4 ha1 = *(const f32x4*)(hra + o * 12 + 4);
            const f32x4 ha2 = *(const f32x4*)(hra + o * 12 + 8);
            const f32x4 hb0 = *(const f32x4*)(hrb + o * 12);
            const f32x4 hb1 = *(const f32x4*)(hrb + o * 12 + 4);
            const f32x4 hb2 = *(const f32x4*)(hrb + o * 12 + 8);
            const f32x2 hha[6] = { ha0.xy, ha0.zw, ha1.xy, ha1.zw, ha2.xy, ha2.zw };
            const f32x2 hhb[6] = { hb0.xy, hb0.zw, hb1.xy, hb1.zw, hb2.xy, hb2.zw };

            float hv[3][2];
            #pragma unroll
            for (int i = 0; i < 3; ++i) {
                f32x2 aRa  = {br[i],  0.f}, aUa  = {bu[i],  0.f};
                f32x2 aXNa = {bxn[i], 0.f}, aHNa = {bhn[i], 0.f};
                f32x2 aRb  = {br[i],  0.f}, aUb  = {bu[i],  0.f};
                f32x2 aXNb = {bxn[i], 0.f}, aHNb = {bhn[i], 0.f};

                aRa  = __builtin_elementwise_fma(wir[i][0], z4a.xy, aRa);
                aRb  = __builtin_elementwise_fma(wir[i][0], z4b.xy, aRb);
                aRa  = __builtin_elementwise_fma(wir[i][1], z4a.zw, aRa);
                aRb  = __builtin_elementwise_fma(wir[i][1], z4b.zw, aRb);
                aUa  = __builtin_elementwise_fma(wiu[i][0], z4a.xy, aUa);
                aUb  = __builtin_elementwise_fma(wiu[i][0], z4b.xy, aUb);
                aUa  = __builtin_elementwise_fma(wiu[i][1], z4a.zw, aUa);
                aUb  = __builtin_elementwise_fma(wiu[i][1], z4b.zw, aUb);
                aXNa = __builtin_elementwise_fma(win[i][0], z4a.xy, aXNa);
                aXNb = __builtin_elementwise_fma(win[i][0], z4b.xy, aXNb);
                aXNa = __builtin_elementwise_fma(win[i][1], z4a.zw, aXNa);
                aXNb = __builtin_elementwise_fma(win[i][1], z4b.zw, aXNb);

                #pragma unroll
                for (int k = 0; k < 6; ++k) {
                    aRa  = __builtin_elementwise_fma(whr[i][k], hha[k], aRa);
                    aRb  = __builtin_elementwise_fma(whr[i][k], hhb[k], aRb);
                    aUa  = __builtin_elementwise_fma(whu[i][k], hha[k], aUa);
                    aUb  = __builtin_elementwise_fma(whu[i][k], hhb[k], aUb);
                    aHNa = __builtin_elementwise_fma(whn[i][k], hha[k], aHNa);
                    aHNb = __builtin_elementwise_fma(whn[i][k], hhb[k], aHNb);
                }

                float sRa  = octet_reduce_lane0(aRa.x  + aRa.y);
                float sRb  = octet_reduce_lane0(aRb.x  + aRb.y);
                float sUa  = octet_reduce_lane0(aUa.x  + aUa.y);
                float sUb  = octet_reduce_lane0(aUb.x  + aUb.y);
                float sXNa = octet_reduce_lane0(aXNa.x + aXNa.y);
                float sXNb = octet_reduce_lane0(aXNb.x + aXNb.y);
                float sHNa = octet_reduce_lane0(aHNa.x + aHNa.y);
                float sHNb = octet_reduce_lane0(aHNb.x + aHNb.y);

                float ra = __builtin_amdgcn_rcpf(1.f + EXP2(-sRa));
                float rb = __builtin_amdgcn_rcpf(1.f + EXP2(-sRb));
                float ua = __builtin_amdgcn_rcpf(1.f + EXP2(-sUa));
                float ub = __builtin_amdgcn_rcpf(1.f + EXP2(-sUb));
                float na = 1.f - 2.f * __builtin_amdgcn_rcpf(1.f + EXP2(sXNa + ra * sHNa));
                float nb = 1.f - 2.f * __builtin_amdgcn_rcpf(1.f + EXP2(sXNb + rb * sHNb));
                hv[i][0] = ua * (hown[i][0] - na) + na;
                hv[i][1] = ub * (hown[i][1] - nb) + nb;
                hown[i][0] = hv[i][0];
                hown[i][1] = hv[i][1];
            }
            if (o == 0) {
                float* hwa = shp[0][pw];
                float* hwb = shp[1][pw];
                hwa[j0]      = hv[0][0];  hwb[j0]      = hv[0][1];
                hwa[j0 + 32] = hv[1][0];  hwb[j0 + 32] = hv[1][1];
                hwa[j0 + 64] = hv[2][0];  hwb[j0 + 64] = hv[2][1];
            }
            __syncthreads();                    // the ONLY barrier per step
        }
    }

    // ---- fused head for both b's ----
    if (tid < 64) {
        const int bb = tid >> 5, m = tid & 31;
        const float* h = shp[bb][0];            // TT even -> final h in pp 0
        float a0 = 0.f, a1 = 0.f, a2 = 0.f, a3 = 0.f;
        #pragma unroll
        for (int kc = 0; kc < HID / 4; ++kc) {
            f32x4 wv = *(const f32x4*)(Whead + (size_t)m * HID + kc * 4);
            f32x4 hv4 = *(const f32x4*)(h + kc * 4);
            a0 += wv.x * hv4.x; a1 += wv.y * hv4.y;
            a2 += wv.z * hv4.z; a3 += wv.w * hv4.w;
        }
        szn[bb][m] = bhead[m] + ((a0 + a1) + (a2 + a3));
    }
    __syncthreads();
    #pragma unroll
    for (int bb = 0; bb < 2; ++bb) {
        #pragma unroll
        for (int r2 = 0; r2 < 2; ++r2) {
            const int col = tid + 256 * r2;
            float acc = 0.f;
            #pragma unroll
            for (int m = 0; m < MIXD; ++m)
                acc += szn[bb][m] * Wmix[(size_t)m * IDIM + col];
            y[(size_t)(b0 + bb) * IDIM + col] = acc;
        }
    }
}

extern "C" void kernel_launch(void* const* d_in, const int* in_sizes, int n_in,
                              void* d_out, int out_size, void* d_ws, size_t ws_size,
                              hipStream_t stream) {
    const float* x     = (const float*)d_in[0];
    const float* Wmix  = (const float*)d_in[1];
    const float* Wih   = (const float*)d_in[2];
    const float* Whh   = (const float*)d_in[3];
    const float* bih   = (const float*)d_in[4];
    const float* bhh   = (const float*)d_in[5];
    const float* Whead = (const float*)d_in[6];
    const float* bhead = (const float*)d_in[7];
    float* out = (float*)d_out;

    float* z = (float*)d_ws;   // [B*T, 32] = 16.78 MB

    k_mix <<<512, 256, 0, stream>>>(x, Wmix, z);
    k_scan<<<BB / 2, 256, 0, stream>>>(z, Wih, Whh, bih, bhh, Whead, bhead, Wmix, out);
}

// Round 14
// 385.816 us; speedup vs baseline: 1.4824x; 1.4824x over previous
//
#include <hip/hip_runtime.h>

#define IDIM 512
#define MIXD 32
#define HID 96
#define BB 256
#define TT 512
#define TROWS 32
#define SROW 516   // padded LDS row stride (floats): bank = 129*r + ... spreads rows

typedef float f32x2 __attribute__((ext_vector_type(2)));
typedef float f32x4 __attribute__((ext_vector_type(4)));

#define EXP2(x) __builtin_amdgcn_exp2f(x)

template <int CTRL>
__device__ __forceinline__ float dpp_shl_add(float x) {
    int m = __builtin_amdgcn_update_dpp(0, __float_as_int(x), CTRL, 0xf, 0xf, true);
    return x + __int_as_float(m);
}
__device__ __forceinline__ float octet_reduce_lane0(float x) {
    x = dpp_shl_add<0x104>(x);   // row_shl:4
    x = dpp_shl_add<0x102>(x);   // row_shl:2
    x = dpp_shl_add<0x101>(x);   // row_shl:1
    return x;
}
// Reduce each 16-lane DPP row into its lane 0 (ks==0).
__device__ __forceinline__ float red16(float x) {
    x = dpp_shl_add<0x108>(x);   // row_shl:8
    x = dpp_shl_add<0x104>(x);
    x = dpp_shl_add<0x102>(x);
    x = dpp_shl_add<0x101>(x);
    return x;
}

// ---------------- K1: z = x @ W_mix^T -----------------------------------
// R12 version was LDS-INSTRUCTION-bound: 8-way-broadcast b128 reads moved
// only 128 B/instr (512 instr/wave/tile = 24.6K cy/tile, matches 84 us).
// v6: thread (mg = tid>>4 owns m = {2mg, 2mg+1}; ks = tid&15 owns 32-float
// k-slice) -> each b128 instr covers 16 DISTINCT addrs (4-way mg-broadcast)
// = 256 B/instr, 2x fewer LDS instr. SROW=516 pad + ks-rotated chunk order
// -> only free 2-way bank conflicts. red16 reduce, ks==0 stores f32x2.
__global__ __launch_bounds__(256) void k_mix(const float* __restrict__ x,
                                             const float* __restrict__ Wmix,
                                             float* __restrict__ z) {
    __shared__ __align__(16) float sx[TROWS * SROW];   // 66 KB
    const int tid = threadIdx.x;
    const int mg = tid >> 4, ks = tid & 15;

    // W rows 2mg, 2mg+1; k-slice [32ks, 32ks+32) in rotated chunk order
    f32x2 w0[16], w1[16];
    #pragma unroll
    for (int i = 0; i < 8; ++i) {
        const int cj = (i + ks) & 7;
        f32x4 v0 = *(const f32x4*)(Wmix + (size_t)(2 * mg)     * IDIM + ks * 32 + cj * 4);
        f32x4 v1 = *(const f32x4*)(Wmix + (size_t)(2 * mg + 1) * IDIM + ks * 32 + cj * 4);
        w0[2*i] = v0.xy; w0[2*i+1] = v0.zw;
        w1[2*i] = v1.xy; w1[2*i+1] = v1.zw;
    }

    const size_t rowbase = (size_t)blockIdx.x * 256;
    const float* xb = x + rowbase * IDIM;

    f32x4 st[16];
    #pragma unroll
    for (int i = 0; i < 16; ++i)                       // tile 0 -> regs
        st[i] = *(const f32x4*)(xb + (size_t)(tid + 256 * i) * 4);

    for (int t = 0; t < 8; ++t) {
        #pragma unroll
        for (int i = 0; i < 16; ++i) {                 // regs -> LDS (padded rows)
            const int v = tid + 256 * i, r = v >> 7, c = v & 127;
            *(f32x4*)(&sx[r * SROW + c * 4]) = st[i];
        }
        __syncthreads();                               // tile t visible

        if (t + 1 < 8) {                               // issue tile t+1 loads
            const float* xn = xb + (size_t)(t + 1) * TROWS * IDIM;
            #pragma unroll
            for (int i = 0; i < 16; ++i)
                st[i] = *(const f32x4*)(xn + (size_t)(tid + 256 * i) * 4);
        }

        float* zp = z + (rowbase + (size_t)t * TROWS) * MIXD + 2 * mg;
        for (int r = 0; r < TROWS; ++r) {
            const float* rp = sx + r * SROW + ks * 32;
            f32x2 a0 = {0.f, 0.f}, a1 = {0.f, 0.f};
            #pragma unroll
            for (int i = 0; i < 8; ++i) {
                f32x4 v = *(const f32x4*)(rp + ((i + ks) & 7) * 4);
                a0 = __builtin_elementwise_fma(w0[2*i],   v.xy, a0);
                a0 = __builtin_elementwise_fma(w0[2*i+1], v.zw, a0);
                a1 = __builtin_elementwise_fma(w1[2*i],   v.xy, a1);
                a1 = __builtin_elementwise_fma(w1[2*i+1], v.zw, a1);
            }
            float s0 = red16(a0.x + a0.y);
            float s1 = red16(a1.x + a1.y);
            if (ks == 0) {
                f32x2 o2 = { s0, s1 };
                *(f32x2*)(zp + (size_t)r * MIXD) = o2;
            }
        }
        __syncthreads();                               // done reading tile t
    }
}

// ---------------- K2: GRU scan + head (R12 base + z-hoist + chain split) ----
// 256 threads = 4 waves, grid 256 (1 b/block — R13's 2-b variants regressed).
// NEW vs R12: (1) next step's z4 is read BEFORE the barrier (sz is stable
// within a chunk; compiler can't hoist loads across __syncthreads itself) so
// its ~120 cy LDS latency overlaps the barrier wait; (2) hh accumulators are
// split 2-way (3-deep chains) for tail ILP.
__global__ __launch_bounds__(256, 1) void k_scan(const float* __restrict__ z,
                                                 const float* __restrict__ Wih,
                                                 const float* __restrict__ Whh,
                                                 const float* __restrict__ bih,
                                                 const float* __restrict__ bhh,
                                                 const float* __restrict__ Whead,
                                                 const float* __restrict__ bhead,
                                                 const float* __restrict__ Wmix,
                                                 float* __restrict__ y) {
    const int b   = blockIdx.x;
    const int tid = threadIdx.x;
    const int j0  = tid >> 3;     // 0..31
    const int o   = tid & 7;      // 0..7
    const float L  = 1.4426950408889634f;   // log2(e)
    const float L2 = 2.8853900817779268f;   // 2*log2(e)

    __shared__ __align__(16) float sz[256 * MIXD];   // 32 KB: half of the z row
    __shared__ __align__(16) float shp[2][HID];      // h ping-pong
    __shared__ __align__(16) float szn[MIXD];

    f32x2 whr[3][6], whu[3][6], whn[3][6], wir[3][2], wiu[3][2], win[3][2];
    float br[3], bu[3], bxn[3], bhn[3];
    #pragma unroll
    for (int i = 0; i < 3; ++i) {
        const int j = j0 + 32 * i;
        #pragma unroll
        for (int c = 0; c < 3; ++c) {
            f32x4 v = *(const f32x4*)(Whh + (size_t)(j        ) * HID + o * 12 + c * 4);
            v *= L;  whr[i][2*c] = v.xy; whr[i][2*c+1] = v.zw;
        }
        #pragma unroll
        for (int c = 0; c < 3; ++c) {
            f32x4 v = *(const f32x4*)(Whh + (size_t)(j +   HID) * HID + o * 12 + c * 4);
            v *= L;  whu[i][2*c] = v.xy; whu[i][2*c+1] = v.zw;
        }
        #pragma unroll
        for (int c = 0; c < 3; ++c) {
            f32x4 v = *(const f32x4*)(Whh + (size_t)(j + 2*HID) * HID + o * 12 + c * 4);
            v *= L2; whn[i][2*c] = v.xy; whn[i][2*c+1] = v.zw;
        }
        {
            f32x4 v = *(const f32x4*)(Wih + (size_t)(j        ) * MIXD + o * 4);
            v *= L;  wir[i][0] = v.xy; wir[i][1] = v.zw;
        }
        {
            f32x4 v = *(const f32x4*)(Wih + (size_t)(j +   HID) * MIXD + o * 4);
            v *= L;  wiu[i][0] = v.xy; wiu[i][1] = v.zw;
        }
        {
            f32x4 v = *(const f32x4*)(Wih + (size_t)(j + 2*HID) * MIXD + o * 4);
            v *= L2; win[i][0] = v.xy; win[i][1] = v.zw;
        }
        br[i]  = (o == 0) ? L  * (bih[j]       + bhh[j])       : 0.f;
        bu[i]  = (o == 0) ? L  * (bih[j + HID] + bhh[j + HID]) : 0.f;
        bxn[i] = (o == 0) ? L2 * bih[j + 2*HID] : 0.f;
        bhn[i] = (o == 0) ? L2 * bhh[j + 2*HID] : 0.f;
    }

    float hown[3] = {0.f, 0.f, 0.f};
    if (tid < HID) shp[0][tid] = 0.f;

    const f32x4* zb4 = (const f32x4*)(z + (size_t)b * TT * MIXD);
    f32x4* sz4 = (f32x4*)sz;

    for (int c = 0; c < TT / 256; ++c) {
        #pragma unroll
        for (int i = 0; i < 8; ++i)
            sz4[tid + 256 * i] = zb4[c * 2048 + tid + 256 * i];
        __syncthreads();

        f32x4 z4 = *(const f32x4*)(sz + 0 * MIXD + o * 4);   // step 0's z
        for (int tt = 0; tt < 256; ++tt) {
            const int t = (c << 8) + tt;
            const float* hr = shp[t & 1];
            float*       hw = shp[(t + 1) & 1];

            const f32x4 h0 = *(const f32x4*)(hr + o * 12);
            const f32x4 h1 = *(const f32x4*)(hr + o * 12 + 4);
            const f32x4 h2 = *(const f32x4*)(hr + o * 12 + 8);
            const f32x2 hh[6] = { h0.xy, h0.zw, h1.xy, h1.zw, h2.xy, h2.zw };

            float hv[3];
            #pragma unroll
            for (int i = 0; i < 3; ++i) {
                // 2-way split accumulators: 3-deep chains instead of 6-deep
                f32x2 aR  = {br[i],  0.f}, aR2  = {0.f, 0.f};
                f32x2 aU  = {bu[i],  0.f}, aU2  = {0.f, 0.f};
                f32x2 aXN = {bxn[i], 0.f};
                f32x2 aHN = {bhn[i], 0.f}, aHN2 = {0.f, 0.f};

                aR  = __builtin_elementwise_fma(wir[i][0], z4.xy, aR);
                aR2 = __builtin_elementwise_fma(wir[i][1], z4.zw, aR2);
                aU  = __builtin_elementwise_fma(wiu[i][0], z4.xy, aU);
                aU2 = __builtin_elementwise_fma(wiu[i][1], z4.zw, aU2);
                aXN = __builtin_elementwise_fma(win[i][0], z4.xy, aXN);
                aXN = __builtin_elementwise_fma(win[i][1], z4.zw, aXN);

                #pragma unroll
                for (int k = 0; k < 3; ++k) {
                    aR   = __builtin_elementwise_fma(whr[i][k],   hh[k],   aR);
                    aR2  = __builtin_elementwise_fma(whr[i][k+3], hh[k+3], aR2);
                    aU   = __builtin_elementwise_fma(whu[i][k],   hh[k],   aU);
                    aU2  = __builtin_elementwise_fma(whu[i][k+3], hh[k+3], aU2);
                    aHN  = __builtin_elementwise_fma(whn[i][k],   hh[k],   aHN);
                    aHN2 = __builtin_elementwise_fma(whn[i][k+3], hh[k+3], aHN2);
                }

                float sR  = octet_reduce_lane0((aR.x  + aR.y)  + (aR2.x  + aR2.y));
                float sU  = octet_reduce_lane0((aU.x  + aU.y)  + (aU2.x  + aU2.y));
                float sXN = octet_reduce_lane0(aXN.x + aXN.y);
                float sHN = octet_reduce_lane0((aHN.x + aHN.y) + (aHN2.x + aHN2.y));

                float r = __builtin_amdgcn_rcpf(1.f + EXP2(-sR));
                float u = __builtin_amdgcn_rcpf(1.f + EXP2(-sU));
                float n = 1.f - 2.f * __builtin_amdgcn_rcpf(1.f + EXP2(sXN + r * sHN));
                hv[i] = u * (hown[i] - n) + n;
                hown[i] = hv[i];
            }
            if (o == 0) {
                hw[j0]      = hv[0];
                hw[j0 + 32] = hv[1];
                hw[j0 + 64] = hv[2];
            }
            // hoist next step's z-read ABOVE the barrier: its LDS latency
            // overlaps the barrier wait (sz is stable within the chunk)
            f32x4 z4n = z4;
            if (tt + 1 < 256) z4n = *(const f32x4*)(sz + (tt + 1) * MIXD + o * 4);
            __syncthreads();
            z4 = z4n;
        }
    }

    // ---- fused head: zn = Whead @ h + bhead ; y = zn @ Wmix ----
    if (tid < MIXD) {
        const float* h = shp[0];                 // TT even -> final h in shp[0]
        float a0 = 0.f, a1 = 0.f, a2 = 0.f, a3 = 0.f;
        #pragma unroll
        for (int kc = 0; kc < HID / 4; ++kc) {
            f32x4 wv = *(const f32x4*)(Whead + (size_t)tid * HID + kc * 4);
            f32x4 hv4 = *(const f32x4*)(h + kc * 4);
            a0 += wv.x * hv4.x; a1 += wv.y * hv4.y;
            a2 += wv.z * hv4.z; a3 += wv.w * hv4.w;
        }
        szn[tid] = bhead[tid] + ((a0 + a1) + (a2 + a3));
    }
    __syncthreads();
    #pragma unroll
    for (int rep = 0; rep < 2; ++rep) {
        const int col = tid + 256 * rep;
        float acc = 0.f;
        #pragma unroll
        for (int m = 0; m < MIXD; ++m)
            acc += szn[m] * Wmix[(size_t)m * IDIM + col];
        y[(size_t)b * IDIM + col] = acc;
    }
}

extern "C" void kernel_launch(void* const* d_in, const int* in_sizes, int n_in,
                              void* d_out, int out_size, void* d_ws, size_t ws_size,
                              hipStream_t stream) {
    const float* x     = (const float*)d_in[0];
    const float* Wmix  = (const float*)d_in[1];
    const float* Wih   = (const float*)d_in[2];
    const float* Whh   = (const float*)d_in[3];
    const float* bih   = (const float*)d_in[4];
    const float* bhh   = (const float*)d_in[5];
    const float* Whead = (const float*)d_in[6];
    const float* bhead = (const float*)d_in[7];
    float* out = (float*)d_out;

    float* z = (float*)d_ws;   // [B*T, 32] = 16.78 MB

    k_mix <<<512, 256, 0, stream>>>(x, Wmix, z);
    k_scan<<<BB,  256, 0, stream>>>(z, Wih, Whh, bih, bhh, Whead, bhead, Wmix, out);
}

// Round 15
// 352.753 us; speedup vs baseline: 1.6214x; 1.0937x over previous
//
#include <hip/hip_runtime.h>

#define IDIM 512
#define MIXD 32
#define HID 96
#define BB 256
#define TT 512
#define TROWS 32
#define SROW 516   // padded LDS row stride (floats)

typedef float f32x2 __attribute__((ext_vector_type(2)));
typedef float f32x4 __attribute__((ext_vector_type(4)));

#define EXP2(x) __builtin_amdgcn_exp2f(x)

template <int CTRL>
__device__ __forceinline__ float dpp_shl_add(float x) {
    int m = __builtin_amdgcn_update_dpp(0, __float_as_int(x), CTRL, 0xf, 0xf, true);
    return x + __int_as_float(m);
}
__device__ __forceinline__ float octet_reduce_lane0(float x) {
    x = dpp_shl_add<0x104>(x);   // row_shl:4
    x = dpp_shl_add<0x102>(x);   // row_shl:2
    x = dpp_shl_add<0x101>(x);   // row_shl:1
    return x;
}
__device__ __forceinline__ float red16(float x) {
    x = dpp_shl_add<0x108>(x);   // row_shl:8
    x = dpp_shl_add<0x104>(x);
    x = dpp_shl_add<0x102>(x);
    x = dpp_shl_add<0x101>(x);
    return x;
}
// Force packed fp32 FMA (VOP3P). R14 analysis: scan VALU-busy is ~2x the
// packed-fma static count -> suspect __builtin_elementwise_fma scalarizes.
__device__ __forceinline__ f32x2 pkfma(f32x2 a, f32x2 b, f32x2 c) {
    asm("v_pk_fma_f32 %0, %1, %2, %0" : "+v"(c) : "v"(a), "v"(b));
    return c;
}

// ---------------- K1: z = x @ W_mix^T (v7: 4 m-rows/thread) -----------------
// R12/v6 was LDS-pipe bound (8 waves/CU x ~260 b128/tile x 12cy ~= 80us).
// v7: thread (mg = (tid>>4)&7 owns m = 4mg..4mg+3; ks = tid&15 owns 32-float
// k-slice; rr = tid>>7 row-half) -> same 8 ds_read_b128 per row now feed
// 128 MACs (4 m's). LDS reads per tile per thread: 16 rows x 8 = 128 (half
// of v6). W regs 4x16xf32x2 = 128 VGPR. red16 reduce, ks==0 stores f32x4.
__global__ __launch_bounds__(256) void k_mix(const float* __restrict__ x,
                                             const float* __restrict__ Wmix,
                                             float* __restrict__ z) {
    __shared__ __align__(16) float sx[TROWS * SROW];   // 66 KB
    const int tid = threadIdx.x;
    const int mg = (tid >> 4) & 7, ks = tid & 15, rr = tid >> 7;

    // W rows 4mg..4mg+3, k-slice [32ks,32ks+32), rotated chunk order
    f32x2 w[4][16];
    #pragma unroll
    for (int mm = 0; mm < 4; ++mm) {
        #pragma unroll
        for (int i = 0; i < 8; ++i) {
            const int cj = (i + ks) & 7;
            f32x4 v = *(const f32x4*)(Wmix + (size_t)(4 * mg + mm) * IDIM + ks * 32 + cj * 4);
            w[mm][2*i] = v.xy; w[mm][2*i+1] = v.zw;
        }
    }

    const size_t rowbase = (size_t)blockIdx.x * 256;
    const float* xb = x + rowbase * IDIM;

    f32x4 st[16];
    #pragma unroll
    for (int i = 0; i < 16; ++i)                       // tile 0 -> regs
        st[i] = *(const f32x4*)(xb + (size_t)(tid + 256 * i) * 4);

    for (int t = 0; t < 8; ++t) {
        #pragma unroll
        for (int i = 0; i < 16; ++i) {                 // regs -> LDS (padded rows)
            const int v = tid + 256 * i, r = v >> 7, c = v & 127;
            *(f32x4*)(&sx[r * SROW + c * 4]) = st[i];
        }
        __syncthreads();                               // tile t visible

        if (t + 1 < 8) {                               // issue tile t+1 loads
            const float* xn = xb + (size_t)(t + 1) * TROWS * IDIM;
            #pragma unroll
            for (int i = 0; i < 16; ++i)
                st[i] = *(const f32x4*)(xn + (size_t)(tid + 256 * i) * 4);
        }

        float* zp = z + (rowbase + (size_t)t * TROWS) * MIXD + 4 * mg;
        for (int rl = 0; rl < 16; ++rl) {
            const int r = rr * 16 + rl;
            const float* rp = sx + r * SROW + ks * 32;
            f32x2 a0 = {0.f,0.f}, a1 = {0.f,0.f}, a2 = {0.f,0.f}, a3 = {0.f,0.f};
            #pragma unroll
            for (int i = 0; i < 8; ++i) {
                f32x4 v = *(const f32x4*)(rp + ((i + ks) & 7) * 4);
                a0 = pkfma(w[0][2*i], v.xy, a0); a0 = pkfma(w[0][2*i+1], v.zw, a0);
                a1 = pkfma(w[1][2*i], v.xy, a1); a1 = pkfma(w[1][2*i+1], v.zw, a1);
                a2 = pkfma(w[2][2*i], v.xy, a2); a2 = pkfma(w[2][2*i+1], v.zw, a2);
                a3 = pkfma(w[3][2*i], v.xy, a3); a3 = pkfma(w[3][2*i+1], v.zw, a3);
            }
            float s0 = red16(a0.x + a0.y);
            float s1 = red16(a1.x + a1.y);
            float s2 = red16(a2.x + a2.y);
            float s3 = red16(a3.x + a3.y);
            if (ks == 0) {
                f32x4 o4 = { s0, s1, s2, s3 };
                *(f32x4*)(zp + (size_t)r * MIXD) = o4;
            }
        }
        __syncthreads();                               // done reading tile t
    }
}

// ---------------- K2: GRU scan + head (EXACT R12 body, pk_fma forced) -------
__global__ __launch_bounds__(256, 1) void k_scan(const float* __restrict__ z,
                                                 const float* __restrict__ Wih,
                                                 const float* __restrict__ Whh,
                                                 const float* __restrict__ bih,
                                                 const float* __restrict__ bhh,
                                                 const float* __restrict__ Whead,
                                                 const float* __restrict__ bhead,
                                                 const float* __restrict__ Wmix,
                                                 float* __restrict__ y) {
    const int b   = blockIdx.x;
    const int tid = threadIdx.x;
    const int j0  = tid >> 3;     // 0..31
    const int o   = tid & 7;      // 0..7
    const float L  = 1.4426950408889634f;   // log2(e)
    const float L2 = 2.8853900817779268f;   // 2*log2(e)

    __shared__ __align__(16) float sz[256 * MIXD];   // 32 KB: half of the z row
    __shared__ __align__(16) float shp[2][HID];      // h ping-pong
    __shared__ __align__(16) float szn[MIXD];

    f32x2 whr[3][6], whu[3][6], whn[3][6], wir[3][2], wiu[3][2], win[3][2];
    float br[3], bu[3], bxn[3], bhn[3];
    #pragma unroll
    for (int i = 0; i < 3; ++i) {
        const int j = j0 + 32 * i;
        #pragma unroll
        for (int c = 0; c < 3; ++c) {
            f32x4 v = *(const f32x4*)(Whh + (size_t)(j        ) * HID + o * 12 + c * 4);
            v *= L;  whr[i][2*c] = v.xy; whr[i][2*c+1] = v.zw;
        }
        #pragma unroll
        for (int c = 0; c < 3; ++c) {
            f32x4 v = *(const f32x4*)(Whh + (size_t)(j +   HID) * HID + o * 12 + c * 4);
            v *= L;  whu[i][2*c] = v.xy; whu[i][2*c+1] = v.zw;
        }
        #pragma unroll
        for (int c = 0; c < 3; ++c) {
            f32x4 v = *(const f32x4*)(Whh + (size_t)(j + 2*HID) * HID + o * 12 + c * 4);
            v *= L2; whn[i][2*c] = v.xy; whn[i][2*c+1] = v.zw;
        }
        {
            f32x4 v = *(const f32x4*)(Wih + (size_t)(j        ) * MIXD + o * 4);
            v *= L;  wir[i][0] = v.xy; wir[i][1] = v.zw;
        }
        {
            f32x4 v = *(const f32x4*)(Wih + (size_t)(j +   HID) * MIXD + o * 4);
            v *= L;  wiu[i][0] = v.xy; wiu[i][1] = v.zw;
        }
        {
            f32x4 v = *(const f32x4*)(Wih + (size_t)(j + 2*HID) * MIXD + o * 4);
            v *= L2; win[i][0] = v.xy; win[i][1] = v.zw;
        }
        br[i]  = (o == 0) ? L  * (bih[j]       + bhh[j])       : 0.f;
        bu[i]  = (o == 0) ? L  * (bih[j + HID] + bhh[j + HID]) : 0.f;
        bxn[i] = (o == 0) ? L2 * bih[j + 2*HID] : 0.f;
        bhn[i] = (o == 0) ? L2 * bhh[j + 2*HID] : 0.f;
    }

    float hown[3] = {0.f, 0.f, 0.f};
    if (tid < HID) shp[0][tid] = 0.f;

    const f32x4* zb4 = (const f32x4*)(z + (size_t)b * TT * MIXD);
    f32x4* sz4 = (f32x4*)sz;

    for (int c = 0; c < TT / 256; ++c) {
        #pragma unroll
        for (int i = 0; i < 8; ++i)
            sz4[tid + 256 * i] = zb4[c * 2048 + tid + 256 * i];
        __syncthreads();

        for (int tt = 0; tt < 256; ++tt) {
            const int t = (c << 8) + tt;
            const float* hr = shp[t & 1];
            float*       hw = shp[(t + 1) & 1];

            const f32x4 z4 = *(const f32x4*)(sz + tt * MIXD + o * 4);
            const f32x4 h0 = *(const f32x4*)(hr + o * 12);
            const f32x4 h1 = *(const f32x4*)(hr + o * 12 + 4);
            const f32x4 h2 = *(const f32x4*)(hr + o * 12 + 8);
            const f32x2 hh[6] = { h0.xy, h0.zw, h1.xy, h1.zw, h2.xy, h2.zw };

            float hv[3];
            #pragma unroll
            for (int i = 0; i < 3; ++i) {
                f32x2 aR  = {br[i],  0.f}, aU  = {bu[i],  0.f};
                f32x2 aXN = {bxn[i], 0.f}, aHN = {bhn[i], 0.f};

                aR  = pkfma(wir[i][0], z4.xy, aR);
                aR  = pkfma(wir[i][1], z4.zw, aR);
                aU  = pkfma(wiu[i][0], z4.xy, aU);
                aU  = pkfma(wiu[i][1], z4.zw, aU);
                aXN = pkfma(win[i][0], z4.xy, aXN);
                aXN = pkfma(win[i][1], z4.zw, aXN);

                #pragma unroll
                for (int k = 0; k < 6; ++k) {
                    aR  = pkfma(whr[i][k], hh[k], aR);
                    aU  = pkfma(whu[i][k], hh[k], aU);
                    aHN = pkfma(whn[i][k], hh[k], aHN);
                }

                float sR  = octet_reduce_lane0(aR.x  + aR.y);
                float sU  = octet_reduce_lane0(aU.x  + aU.y);
                float sXN = octet_reduce_lane0(aXN.x + aXN.y);
                float sHN = octet_reduce_lane0(aHN.x + aHN.y);

                float r = __builtin_amdgcn_rcpf(1.f + EXP2(-sR));
                float u = __builtin_amdgcn_rcpf(1.f + EXP2(-sU));
                float n = 1.f - 2.f * __builtin_amdgcn_rcpf(1.f + EXP2(sXN + r * sHN));
                hv[i] = u * (hown[i] - n) + n;   // lane0 correct; others garbage
                hown[i] = hv[i];
            }
            if (o == 0) {
                hw[j0]      = hv[0];
                hw[j0 + 32] = hv[1];
                hw[j0 + 64] = hv[2];
            }
            __syncthreads();                    // the ONLY barrier per step
        }
    }

    // ---- fused head: zn = Whead @ h + bhead ; y = zn @ Wmix ----
    if (tid < MIXD) {
        const float* h = shp[0];                 // TT even -> final h in shp[0]
        float a0 = 0.f, a1 = 0.f, a2 = 0.f, a3 = 0.f;
        #pragma unroll
        for (int kc = 0; kc < HID / 4; ++kc) {
            f32x4 wv = *(const f32x4*)(Whead + (size_t)tid * HID + kc * 4);
            f32x4 hv4 = *(const f32x4*)(h + kc * 4);
            a0 += wv.x * hv4.x; a1 += wv.y * hv4.y;
            a2 += wv.z * hv4.z; a3 += wv.w * hv4.w;
        }
        szn[tid] = bhead[tid] + ((a0 + a1) + (a2 + a3));
    }
    __syncthreads();
    #pragma unroll
    for (int rep = 0; rep < 2; ++rep) {
        const int col = tid + 256 * rep;
        float acc = 0.f;
        #pragma unroll
        for (int m = 0; m < MIXD; ++m)
            acc += szn[m] * Wmix[(size_t)m * IDIM + col];
        y[(size_t)b * IDIM + col] = acc;
    }
}

extern "C" void kernel_launch(void* const* d_in, const int* in_sizes, int n_in,
                              void* d_out, int out_size, void* d_ws, size_t ws_size,
                              hipStream_t stream) {
    const float* x     = (const float*)d_in[0];
    const float* Wmix  = (const float*)d_in[1];
    const float* Wih   = (const float*)d_in[2];
    const float* Whh   = (const float*)d_in[3];
    const float* bih   = (const float*)d_in[4];
    const float* bhh   = (const float*)d_in[5];
    const float* Whead = (const float*)d_in[6];
    const float* bhead = (const float*)d_in[7];
    float* out = (float*)d_out;

    float* z = (float*)d_ws;   // [B*T, 32] = 16.78 MB

    k_mix <<<512, 256, 0, stream>>>(x, Wmix, z);
    k_scan<<<BB,  256, 0, stream>>>(z, Wih, Whh, bih, bhh, Whead, bhead, Wmix, out);
}